// Round 2
// baseline (244.656 us; speedup 1.0000x reference)
//
#include <hip/hip_runtime.h>

// RSNN: B=32, T=500, N_IN=512, N_HID=2048.
// Key mathematical fact: reset = (mem > -55). Once ALL neurons of a batch have
// mem > -55 at the top of a step, mem becomes exactly 0 for all of them
// (mem = base*(1-reset)), and mem==0 > -55 is absorbing: the input/recurrent
// matmuls are multiplied by exactly 0.0 forever after. From that step on the
// output is a closed-form refractory state machine (period-5 spiking).
//
// Kernel 1 (scan): faithful general recurrence with a per-step block vote;
//   exits to "fast mode" permanently when the vote proves absorption.
//   Vote is a single __syncthreads_or.
// Kernel 2 (expand): writes the closed-form spike pattern for t >= t_entry[b].
//   64 B/thread (4x 16B nontemporal stores via clang ext_vector — HIP float4
//   is a class type that __builtin_nontemporal_store rejects), one uint4
//   refrac load per thread. Predicate reduced to (s % 5 == s0): s >= s0 is
//   implied by sm == s0 because s >= s%5 always and s0 in [0,4].
// For the benchmark data the vote succeeds at t=0, so kernel 2 (pure 131 MB
// stream write) dominates: HBM-write-bound, target = fill-kernel rate 7 TB/s.

#define T_STEPS   500
#define BATCH     32
#define N_INP     512
#define N_HID     2048
#define THRESH    (-55.0f)
#define BETA_V    0.95f
#define REST      70.0f
#define REFRAC_P  5

typedef float f32x4 __attribute__((ext_vector_type(4)));

__global__ __launch_bounds__(1024) void rsnn_scan(
    const float* __restrict__ x,       // [B, T, N_INP]
    const float* __restrict__ mem0,    // [B, N_HID]
    const float* __restrict__ W_in,    // [N_HID, N_INP]
    const float* __restrict__ b_in,    // [N_HID]
    const float* __restrict__ W_rec,   // [N_HID, N_HID]
    const float* __restrict__ b_rec,   // [N_HID]
    float* __restrict__ out,           // [T, B, N_HID]
    int* __restrict__ tEntry,          // [B]
    unsigned char* __restrict__ refracOut) // [B, N_HID]
{
    const int b   = blockIdx.x;
    const int tid = threadIdx.x;
    const int h0  = tid * 2;           // two consecutive neurons per thread

    __shared__ float spkLDS[N_HID];

    const float2 m2 = *reinterpret_cast<const float2*>(mem0 + (size_t)b * N_HID + h0);
    float mem[2] = { m2.x, m2.y };
    int   rr[2]  = { 0, 0 };
    float spk[2] = { 0.f, 0.f };

    spkLDS[h0]     = 0.f;
    spkLDS[h0 + 1] = 0.f;

    int te = T_STEPS;

    for (int t = 0; t < T_STEPS; ++t) {
        // Block-wide vote: one barrier. Also orders spkLDS writes (below)
        // before the slow path's reads, and the init stores before t=0.
        const int bad = (!(mem[0] > THRESH)) | (!(mem[1] > THRESH));
        if (__syncthreads_or(bad) == 0) { te = t; break; }  // absorbing fast mode

        // ---- general (slow) step — never executed on benchmark data ----
#pragma unroll
        for (int j = 0; j < 2; ++j) {
            const int h = h0 + j;
            rr[j] = max(rr[j] - 1, 0);
            const bool reset = (mem[j] > THRESH);
            float m;
            if (!reset) {
                float rec = 0.f;
                const float* wr = W_rec + (size_t)h * N_HID;
                for (int k = 0; k < N_HID; ++k) rec += spkLDS[k] * wr[k];
                float cur = b_in[h];
                const float* xi = x + ((size_t)b * T_STEPS + t) * N_INP;
                const float* wi = W_in + (size_t)h * N_INP;
                for (int k = 0; k < N_INP; ++k) cur += xi[k] * wi[k];
                m = BETA_V * (mem[j] + REST) + cur + rec + b_rec[h] - REST;
            } else {
                m = 0.f;
            }
            mem[j] = m;
            spk[j] = ((mem[j] > THRESH) && (rr[j] == 0)) ? 1.f : 0.f;
            if (spk[j] > 0.f) rr[j] = REFRAC_P;
            out[(size_t)t * (BATCH * N_HID) + (size_t)b * N_HID + h] = spk[j];
        }
        __syncthreads();  // finish spkLDS reads before overwrite
        spkLDS[h0]     = spk[0];
        spkLDS[h0 + 1] = spk[1];
        // next iteration's vote barrier orders these writes before reads
    }

    uchar2 rw;
    rw.x = (unsigned char)rr[0];
    rw.y = (unsigned char)rr[1];
    *reinterpret_cast<uchar2*>(refracOut + (size_t)b * N_HID + h0) = rw;
    if (tid == 0) tEntry[b] = te;
}

// One thread per 16 consecutive output elements (same t, same b: 16 | 2048).
// 4000 blocks x 512 threads covers 500*32*2048 = 32,768,000 elements exactly.
__global__ __launch_bounds__(512) void rsnn_expand(
    float* __restrict__ out,
    const int* __restrict__ tEntry,
    const unsigned char* __restrict__ refrac)
{
    const unsigned base = (blockIdx.x * 512u + threadIdx.x) * 16u; // elem index
    const int t   = (int)(base >> 16);        // B*N_HID = 65536 = 2^16
    const int rem = (int)(base & 65535u);
    const int b   = rem >> 11;                // N_HID = 2048 = 2^11
    const int h   = rem & 2047;

    const int te = tEntry[b];
    if (t < te) return;                       // slow region already written by scan

    const int s  = t - te;
    const int sm = s % 5;

    // 16 refrac bytes in one dwordx4 load (base is 16-aligned, 16 | 2048)
    const uint4 Rv = *reinterpret_cast<const uint4*>(refrac + (size_t)b * N_HID + h);
    const unsigned w0 = Rv.x, w1 = Rv.y, w2 = Rv.z, w3 = Rv.w;

    f32x4* po = reinterpret_cast<f32x4*>(out + base);

    // spike iff s % 5 == s0 where s0 = R ? R-1 : 0   (s >= s0 implied)
#define PAT1(word, sh) ((sm == ((((word) >> (sh)) & 0xffu) ? (int)(((word) >> (sh)) & 0xffu) - 1 : 0)) ? 1.f : 0.f)
#define PAT4(word) ((f32x4){PAT1(word,0), PAT1(word,8), PAT1(word,16), PAT1(word,24)})

    __builtin_nontemporal_store(PAT4(w0), po + 0);
    __builtin_nontemporal_store(PAT4(w1), po + 1);
    __builtin_nontemporal_store(PAT4(w2), po + 2);
    __builtin_nontemporal_store(PAT4(w3), po + 3);

#undef PAT4
#undef PAT1
}

extern "C" void kernel_launch(void* const* d_in, const int* in_sizes, int n_in,
                              void* d_out, int out_size, void* d_ws, size_t ws_size,
                              hipStream_t stream) {
    const float* x     = (const float*)d_in[0];
    const float* mem0  = (const float*)d_in[1];
    const float* W_in  = (const float*)d_in[2];
    const float* b_in  = (const float*)d_in[3];
    const float* W_rec = (const float*)d_in[4];
    const float* b_rec = (const float*)d_in[5];
    float* out = (float*)d_out;

    int* tEntry = (int*)d_ws;                                   // 32 ints
    unsigned char* refrac = (unsigned char*)d_ws + 128;         // B*N_HID bytes

    rsnn_scan<<<BATCH, 1024, 0, stream>>>(x, mem0, W_in, b_in, W_rec, b_rec,
                                          out, tEntry, refrac);

    const unsigned total  = (unsigned)T_STEPS * BATCH * N_HID;  // 32,768,000
    const unsigned blocks = total / (512u * 16u);               // 4,000
    rsnn_expand<<<blocks, 512, 0, stream>>>(out, tEntry, refrac);
}

// Round 3
// 169.395 us; speedup vs baseline: 1.4443x; 1.4443x over previous
//
#include <hip/hip_runtime.h>

// RSNN: B=32, T=500, N_IN=512, N_HID=2048.
// Key mathematical fact: reset = (mem > -55). Once ALL neurons of a batch have
// mem > -55 at the top of a step, mem becomes exactly 0 for all of them
// (mem = base*(1-reset)), and mem==0 > -55 is absorbing: the input/recurrent
// matmuls are multiplied by exactly 0.0 forever after. From that step on the
// output is a closed-form refractory state machine (period-5 spiking).
//
// Kernel 1 (scan): faithful general recurrence with a per-step block vote;
//   exits to "fast mode" permanently when the vote proves absorption.
// Kernel 2 (expand): writes the closed-form spike pattern for t >= t_entry[b].
//   COALESCING LESSON (round 2): 4 consecutive float4 per thread made each
//   store instruction a stride-64B partial-line write; with nt stores the
//   partial sectors flushed to HBM before merging -> WRITE_SIZE 2x (263 MB),
//   2.5 TB/s. Now each block covers 4 whole N_HID rows and chunk k is one
//   row with thread slot tid*4: every store instruction is 64 lanes x 16 B
//   CONTIGUOUS (full lines), nt keeps the 131 MB stream out of L2.
//   t/b/te/sm are wave-uniform per chunk (scalar path, zero divergence).

#define T_STEPS   500
#define BATCH     32
#define N_INP     512
#define N_HID     2048
#define THRESH    (-55.0f)
#define BETA_V    0.95f
#define REST      70.0f
#define REFRAC_P  5

typedef float f32x4 __attribute__((ext_vector_type(4)));

__global__ __launch_bounds__(1024) void rsnn_scan(
    const float* __restrict__ x,       // [B, T, N_INP]
    const float* __restrict__ mem0,    // [B, N_HID]
    const float* __restrict__ W_in,    // [N_HID, N_INP]
    const float* __restrict__ b_in,    // [N_HID]
    const float* __restrict__ W_rec,   // [N_HID, N_HID]
    const float* __restrict__ b_rec,   // [N_HID]
    float* __restrict__ out,           // [T, B, N_HID]
    int* __restrict__ tEntry,          // [B]
    unsigned char* __restrict__ refracOut) // [B, N_HID]
{
    const int b   = blockIdx.x;
    const int tid = threadIdx.x;
    const int h0  = tid * 2;           // two consecutive neurons per thread

    __shared__ float spkLDS[N_HID];

    const float2 m2 = *reinterpret_cast<const float2*>(mem0 + (size_t)b * N_HID + h0);
    float mem[2] = { m2.x, m2.y };
    int   rr[2]  = { 0, 0 };
    float spk[2] = { 0.f, 0.f };

    spkLDS[h0]     = 0.f;
    spkLDS[h0 + 1] = 0.f;

    int te = T_STEPS;

    for (int t = 0; t < T_STEPS; ++t) {
        // Block-wide vote: one barrier. Also orders spkLDS writes (below)
        // before the slow path's reads, and the init stores before t=0.
        const int bad = (!(mem[0] > THRESH)) | (!(mem[1] > THRESH));
        if (__syncthreads_or(bad) == 0) { te = t; break; }  // absorbing fast mode

        // ---- general (slow) step — never executed on benchmark data ----
#pragma unroll
        for (int j = 0; j < 2; ++j) {
            const int h = h0 + j;
            rr[j] = max(rr[j] - 1, 0);
            const bool reset = (mem[j] > THRESH);
            float m;
            if (!reset) {
                float rec = 0.f;
                const float* wr = W_rec + (size_t)h * N_HID;
                for (int k = 0; k < N_HID; ++k) rec += spkLDS[k] * wr[k];
                float cur = b_in[h];
                const float* xi = x + ((size_t)b * T_STEPS + t) * N_INP;
                const float* wi = W_in + (size_t)h * N_INP;
                for (int k = 0; k < N_INP; ++k) cur += xi[k] * wi[k];
                m = BETA_V * (mem[j] + REST) + cur + rec + b_rec[h] - REST;
            } else {
                m = 0.f;
            }
            mem[j] = m;
            spk[j] = ((mem[j] > THRESH) && (rr[j] == 0)) ? 1.f : 0.f;
            if (spk[j] > 0.f) rr[j] = REFRAC_P;
            out[(size_t)t * (BATCH * N_HID) + (size_t)b * N_HID + h] = spk[j];
        }
        __syncthreads();  // finish spkLDS reads before overwrite
        spkLDS[h0]     = spk[0];
        spkLDS[h0 + 1] = spk[1];
        // next iteration's vote barrier orders these writes before reads
    }

    uchar2 rw;
    rw.x = (unsigned char)rr[0];
    rw.y = (unsigned char)rr[1];
    *reinterpret_cast<uchar2*>(refracOut + (size_t)b * N_HID + h0) = rw;
    if (tid == 0) tEntry[b] = te;
}

// Each block (512 threads) covers 4 consecutive rows of [T*B][N_HID]:
// chunk k = row (blockIdx.x*4 + k); thread owns floats [tid*4, tid*4+4) of
// that row. Every 16B store is wave-contiguous (512 lanes span the full
// 8 KB row). 16000 rows -> 4000 blocks.
__global__ __launch_bounds__(512) void rsnn_expand(
    float* __restrict__ out,
    const int* __restrict__ tEntry,
    const unsigned char* __restrict__ refrac)
{
    const int tid  = threadIdx.x;
    const int row0 = blockIdx.x * 4;          // row = t*32 + b
    const int h4   = tid * 4;                 // this thread's slot in each row

#pragma unroll
    for (int k = 0; k < 4; ++k) {
        const int r  = row0 + k;
        const int t  = r >> 5;                // BATCH = 32
        const int b  = r & 31;
        const int te = tEntry[b];             // wave-uniform -> scalar load
        if (t < te) continue;                 // slow region written by scan

        const int sm = (t - te) % 5;          // wave-uniform

        const uchar4 R = *reinterpret_cast<const uchar4*>(
            refrac + (size_t)b * N_HID + h4); // coalesced 4B/lane

        // spike iff (t-te) % 5 == s0, s0 = R ? R-1 : 0  (s >= s0 is implied:
        // s >= s%5 always and s0 in [0,4])
        f32x4 o;
        o.x = (sm == (R.x ? (int)R.x - 1 : 0)) ? 1.f : 0.f;
        o.y = (sm == (R.y ? (int)R.y - 1 : 0)) ? 1.f : 0.f;
        o.z = (sm == (R.z ? (int)R.z - 1 : 0)) ? 1.f : 0.f;
        o.w = (sm == (R.w ? (int)R.w - 1 : 0)) ? 1.f : 0.f;

        __builtin_nontemporal_store(
            o, reinterpret_cast<f32x4*>(out + (size_t)r * N_HID + h4));
    }
}

extern "C" void kernel_launch(void* const* d_in, const int* in_sizes, int n_in,
                              void* d_out, int out_size, void* d_ws, size_t ws_size,
                              hipStream_t stream) {
    const float* x     = (const float*)d_in[0];
    const float* mem0  = (const float*)d_in[1];
    const float* W_in  = (const float*)d_in[2];
    const float* b_in  = (const float*)d_in[3];
    const float* W_rec = (const float*)d_in[4];
    const float* b_rec = (const float*)d_in[5];
    float* out = (float*)d_out;

    int* tEntry = (int*)d_ws;                                   // 32 ints
    unsigned char* refrac = (unsigned char*)d_ws + 128;         // B*N_HID bytes

    rsnn_scan<<<BATCH, 1024, 0, stream>>>(x, mem0, W_in, b_in, W_rec, b_rec,
                                          out, tEntry, refrac);

    const int totalRows = T_STEPS * BATCH;                      // 16000
    const int blocks    = totalRows / 4;                        // 4000
    rsnn_expand<<<blocks, 512, 0, stream>>>(out, tEntry, refrac);
}